// Round 10
// baseline (412.972 us; speedup 1.0000x reference)
//
#include <hip/hip_runtime.h>
#include <math.h>

#define DIM    1024
#define HEADS  16
#define HD     64
#define SEQ    2048
#define BATCH  2
#define TTOK   4096   // BATCH*SEQ
#define DFF    4096
#define S3     3072   // fused QKV row stride
#define NTSW   16     // K-tiles per 1024-chunk (1024/64)

typedef __attribute__((ext_vector_type(8))) short short8;
typedef __attribute__((ext_vector_type(4))) float f32x4;

__device__ __forceinline__ float bf2f(unsigned short u) {
  union { unsigned int u; float f; } v; v.u = ((unsigned int)u) << 16; return v.f;
}
__device__ __forceinline__ unsigned short f2bf(float f) {
  union { float f; unsigned int u; } v; v.f = f;
  return (unsigned short)((v.u + 0x7FFFu + ((v.u >> 16) & 1u)) >> 16);
}
__device__ __forceinline__ unsigned short f2bf_trunc(float f) {
  union { float f; unsigned int u; } v; v.f = f;
  return (unsigned short)(v.u >> 16);
}

#define AS1(p) ((const __attribute__((address_space(1))) void*)(p))
#define AS3(p) ((__attribute__((address_space(3))) void*)(p))

// ---------------------------------------------------------------------------
// Merged weight conversion + rmsnorm1 (independent work, one launch).
// Blocks [0,16384): all 7 f32 weights -> contiguous bf16 [0,16M).
// Regions (4-elem units): wq/wk/wv/wo 262144 each; gate_w/up_w written
// INTERLEAVED at 16-row granularity into [1048576, 3145728) units (rows
// 32t+0..15 = gate rows 16t.., rows 32t+16..31 = up rows 16t..) so SwiGLU
// runs as ONE plain GEMM with N=8192; dw 1048576 units at 3145728.
// Blocks [16384,20480): rmsnorm over h (f32) -> x1 (bf16), t = blk-16384.
// ---------------------------------------------------------------------------
__global__ __launch_bounds__(256) void wconv_rms_k(
    const float* __restrict__ s0, const float* __restrict__ s1,
    const float* __restrict__ s2, const float* __restrict__ s3,
    const float* __restrict__ s4, const float* __restrict__ s5,
    const float* __restrict__ s6, unsigned short* __restrict__ dst,
    const float* __restrict__ X, const float* __restrict__ Wn,
    unsigned short* __restrict__ Y)
{
  __shared__ float red[4];
  if (blockIdx.x < 16384) {
    const int i = blockIdx.x * 256 + threadIdx.x;   // 0..4194303
    const float* s; int base; int di = i;
    if (i < 1048576) {
      if (i < 524288) { if (i < 262144) { s = s0; base = 0; } else { s = s1; base = 262144; } }
      else            { if (i < 786432) { s = s2; base = 524288; } else { s = s3; base = 786432; } }
    } else if (i < 2097152) {
      s = s4; base = 1048576;
      const int u = i - base; const int r = u >> 8; const int c = u & 255;
      di = 1048576 + (((r >> 4) << 5) + (r & 15)) * 256 + c;       // gate rows
    } else if (i < 3145728) {
      s = s5; base = 2097152;
      const int u = i - base; const int r = u >> 8; const int c = u & 255;
      di = 1048576 + (((r >> 4) << 5) + 16 + (r & 15)) * 256 + c;  // up rows
    } else {
      s = s6; base = 3145728;
    }
    const float4 f = ((const float4*)s)[i - base];
    unsigned long long o = (unsigned long long)f2bf(f.x)
                         | ((unsigned long long)f2bf(f.y) << 16)
                         | ((unsigned long long)f2bf(f.z) << 32)
                         | ((unsigned long long)f2bf(f.w) << 48);
    ((unsigned long long*)dst)[di] = o;
  } else {
    const int t  = blockIdx.x - 16384;
    const int i0 = threadIdx.x * 4;
    const float4 f = *(const float4*)(X + (size_t)t * DIM + i0);
    float v[4] = {f.x, f.y, f.z, f.w};
    float ss = v[0] * v[0] + v[1] * v[1] + v[2] * v[2] + v[3] * v[3];
#pragma unroll
    for (int off = 32; off > 0; off >>= 1) ss += __shfl_xor(ss, off);
    if ((threadIdx.x & 63) == 0) red[threadIdx.x >> 6] = ss;
    __syncthreads();
    const float tot = red[0] + red[1] + red[2] + red[3];
    const float r = rsqrtf(tot * (1.0f / DIM) + 1e-5f);
    const float4 wf = *(const float4*)(Wn + i0);
    const float wv4[4] = {wf.x, wf.y, wf.z, wf.w};
    unsigned long long o = 0;
#pragma unroll
    for (int k = 0; k < 4; k++)
      o |= ((unsigned long long)f2bf(v[k] * r * wv4[k])) << (16 * k);
    *(unsigned long long*)(Y + (size_t)t * DIM + i0) = o;
  }
}

// ---------------------------------------------------------------------------
// GEMM: C[M,N] = A[M,K] bf16 x W[N,K]^T bf16. 128x128 tile, BK=64, 4 waves,
// 16x16x32 MFMA, global_load_lds w=16, XOR-8 swizzle.
// MODE 3: Cf = v + resf (f32 out)
// MODE 5: C = v with RoPE on cols<2048 (fused QKV, N=3072)
// MODE 6: split-K partial (grid.z selects K-chunk of 1024 and partial region)
// ---------------------------------------------------------------------------
template<int MODE>
__global__ __launch_bounds__(256) void gemm_bt(
    const unsigned short* __restrict__ A,
    const unsigned short* __restrict__ W,
    unsigned short* __restrict__ C,
    float* __restrict__ Cf,
    const float* __restrict__ resf,
    const float* __restrict__ cosp,
    const float* __restrict__ sinp,
    int M, int N, int K)
{
  __shared__ __align__(16) unsigned short As[128 * 64];
  __shared__ __align__(16) unsigned short Bs[128 * 64];

  const int tid  = threadIdx.x;
  const int lane = tid & 63;
  const int wv   = tid >> 6;
  const int row0 = blockIdx.x * 128;
  const int col0 = blockIdx.y * 128;
  const int wm   = (wv >> 1) * 64;
  const int wn   = (wv & 1) * 64;
  const int lr   = lane & 15;
  const int lg   = lane >> 4;

  const int srow = lane >> 3;
  const int skg  = (lane & 7) ^ srow;

  int kb = 0, ke = K;
  if (MODE == 6) { kb = blockIdx.z * 1024; ke = kb + 1024; }

  f32x4 acc[4][4];
#pragma unroll
  for (int i = 0; i < 4; i++)
#pragma unroll
    for (int j = 0; j < 4; j++) acc[i][j] = (f32x4){0.f, 0.f, 0.f, 0.f};

  for (int k0 = kb; k0 < ke; k0 += 64) {
#pragma unroll
    for (int i = 0; i < 4; i++) {
      const int c = wv * 4 + i;
      const unsigned short* ga = A + (size_t)(row0 + c * 8 + srow) * K + k0 + skg * 8;
      __builtin_amdgcn_global_load_lds(AS1(ga), AS3(As + c * 512), 16, 0, 0);
      const unsigned short* gb = W + (size_t)(col0 + c * 8 + srow) * K + k0 + skg * 8;
      __builtin_amdgcn_global_load_lds(AS1(gb), AS3(Bs + c * 512), 16, 0, 0);
    }
    __syncthreads();

#pragma unroll
    for (int ks = 0; ks < 2; ks++) {
      short8 af[4], bf[4];
#pragma unroll
      for (int i = 0; i < 4; i++) {
        const int r = wm + i * 16 + lr;
        af[i] = *(const short8*)(As + r * 64 + (((ks * 4 + lg) ^ (lr & 7)) * 8));
      }
#pragma unroll
      for (int j = 0; j < 4; j++) {
        const int r = wn + j * 16 + lr;
        bf[j] = *(const short8*)(Bs + r * 64 + (((ks * 4 + lg) ^ (lr & 7)) * 8));
      }
#pragma unroll
      for (int i = 0; i < 4; i++)
#pragma unroll
        for (int j = 0; j < 4; j++)
          acc[i][j] = __builtin_amdgcn_mfma_f32_16x16x32_bf16(af[i], bf[j], acc[i][j], 0, 0, 0);
    }
    __syncthreads();
  }

  // epilogue: C/D layout col=lane&15, row=(lane>>4)*4+r  [m89/m91]
  if (MODE == 5) {
    const bool do_rope = (col0 < 2048);
#pragma unroll
    for (int i = 0; i < 4; i++) {
#pragma unroll
      for (int r = 0; r < 4; r++) {
        const int row = row0 + wm + i * 16 + lg * 4 + r;
        const int s = row & (SEQ - 1);
        const size_t rb = (size_t)row * N + col0 + wn;
        if (do_rope) {
#pragma unroll
          for (int jp = 0; jp < 2; jp++) {
            const int d = jp * 16 + lr;
            const float c = cosp[s * HD + d];
            const float sn = sinp[s * HD + d];
            const float x1v = acc[i][jp][r];
            const float x2v = acc[i][jp + 2][r];
            C[rb + d]      = f2bf(x1v * c - x2v * sn);
            C[rb + d + 32] = f2bf(x2v * c + x1v * sn);
          }
        } else {
#pragma unroll
          for (int j = 0; j < 4; j++)
            C[rb + j * 16 + lr] = f2bf(acc[i][j][r]);
        }
      }
    }
    return;
  }

  unsigned short* Cz = C;
  if (MODE == 6) {
    const size_t pz[4] = {4u * 1048576u, 8u * 1048576u, 16u * 1048576u, 0u};
    Cz = C + pz[blockIdx.z];
  }
#pragma unroll
  for (int i = 0; i < 4; i++) {
#pragma unroll
    for (int j = 0; j < 4; j++) {
      const int col = col0 + wn + j * 16 + lr;
#pragma unroll
      for (int r = 0; r < 4; r++) {
        const int row = row0 + wm + i * 16 + lg * 4 + r;
        const float v = acc[i][j][r];
        const size_t idx = (size_t)row * N + col;
        if (MODE == 3) {
          Cf[idx] = v + resf[idx];
        } else if (MODE == 6) {
          Cz[idx] = f2bf(v);
        }
      }
    }
  }
}

// ---------------------------------------------------------------------------
// 256x256-tile 8-phase SwiGLU GEMM (m201 template port, T2+T3+T4+T5).
// 512 thr / 8 waves (2Mx4N), per-wave 128x64 out, BK=64, 2 K-tiles/iter,
// LDS 128KB (2 dbuf x 32KB x {A,B}). A stored as 4 phase-private 8KB
// quarters; B read whole in each tile's first phase, held in regs.
// vmcnt(6) gates at phases 4/8 only; tail gates drain to 0. XOR-8 chunk
// swizzle via pre-swizzled source; accumulation order identical to the
// 128^2 path (bitwise-same output).
// SwiGLU over 16-row interleaved gate/up W [8192][1024]: frag j even=gate /
// j odd=up on the same lanes; out G[M][DFF]. Scalar-store epilogue: the
// via-LDS coalesced variant did NOT replicate at wall level (R6 396.5 vs
// R9 405.5, only-diff A/B) — keep scalar.
// ---------------------------------------------------------------------------
__global__ __launch_bounds__(512, 2) void gemm256_swiglu(
    const unsigned short* __restrict__ A,    // [4096][1024]
    const unsigned short* __restrict__ W,    // [8192][1024] interleaved gu
    unsigned short* __restrict__ G,          // [4096][4096]
    const float* __restrict__ gbias,
    const float* __restrict__ ubias,
    int colb)
{
  __shared__ __align__(16) unsigned short Asl[2 * 16384];  // 64 KB
  __shared__ __align__(16) unsigned short Bsl[2 * 16384];  // 64 KB

  const int tid  = threadIdx.x;
  const int lane = tid & 63;
  const int wv   = tid >> 6;
  const int row0 = blockIdx.x * 256;
  const int col0 = blockIdx.y * 256 + colb;
  const int wm   = (wv >> 2) * 128;          // 0 | 128
  const int wn   = (wv & 3) * 64;            // 0..192
  const int lr   = lane & 15;
  const int lg   = lane >> 4;

  // staging geometry: thread t covers shorts [t*8, t*8+8) of an 8KB quarter.
  // local row rl = t>>3 (0..63), stored chunk = t&7, logical chunk =
  // stored ^ (rl&7)  (XOR-8 swizzle via pre-swizzled global source).
  const int rl   = tid >> 3;
  const int rq   = (rl & 31) + ((rl >> 5) << 7);   // +q*32 = row within tile
  const int cl8  = ((tid & 7) ^ (rl & 7)) * 8;     // logical col byte-pair off
  const int ldsu = wv * 512;                       // wave-uniform LDS slice

  auto stA = [&](int t, int q) {
    const unsigned short* s = A + (size_t)(row0 + q * 32 + rq) * 1024 + t * 64 + cl8;
    __builtin_amdgcn_global_load_lds(AS1(s), AS3(Asl + (t & 1) * 16384 + q * 4096 + ldsu), 16, 0, 0);
  };
  auto stB = [&](int t, int q) {
    const unsigned short* s = W + (size_t)(col0 + q * 32 + rq) * 1024 + t * 64 + cl8;
    __builtin_amdgcn_global_load_lds(AS1(s), AS3(Bsl + (t & 1) * 16384 + q * 4096 + ldsu), 16, 0, 0);
  };

  f32x4 acc[8][4];
#pragma unroll
  for (int f = 0; f < 8; f++)
#pragma unroll
    for (int j = 0; j < 4; j++) acc[f][j] = (f32x4){0.f, 0.f, 0.f, 0.f};

  // prologue: T0 full (8 units) + T1 {B q0-3, A q0,q1} (6 units)
  stB(0, 0); stB(0, 1); stB(0, 2); stB(0, 3);
  stA(0, 0); stA(0, 1); stA(0, 2); stA(0, 3);
  stB(1, 0); stB(1, 1); stB(1, 2); stB(1, 3);
  stA(1, 0); stA(1, 1);
  asm volatile("s_waitcnt vmcnt(6)" ::: "memory");   // T0 landed; T1x6 in flight
  __builtin_amdgcn_s_barrier();

#pragma unroll 1
  for (int J = 0; J < NTSW / 2; ++J) {
    const int t2 = 2 * J + 2, t3 = 2 * J + 3;
#pragma unroll
    for (int h = 0; h < 2; ++h) {
      const unsigned short* Ab = Asl + h * 16384;   // tile 2J+h, buf = h
      const unsigned short* Bb = Bsl + h * 16384;
      short8 bfr[4][2];
#pragma unroll
      for (int p = 0; p < 4; ++p) {
        // ---- ds reads: B whole tile at p==0, A quarter p each phase ----
        if (p == 0) {
#pragma unroll
          for (int j = 0; j < 4; ++j) {
            const int rn   = wn + j * 16 + lr;
            const int q    = (rn & 127) >> 5;
            const int rloc = (rn & 31) + ((rn >> 7) << 5);
#pragma unroll
            for (int ks = 0; ks < 2; ++ks)
              bfr[j][ks] = *(const short8*)(Bb + q * 4096 + rloc * 64 +
                                            (((ks * 4 + lg) ^ (lr & 7)) * 8));
          }
        }
        short8 af[2][2];
#pragma unroll
        for (int e = 0; e < 2; ++e) {
          const int rloc = e * 16 + lr + ((wv >> 2) << 5);
#pragma unroll
          for (int ks = 0; ks < 2; ++ks)
            af[e][ks] = *(const short8*)(Ab + p * 4096 + rloc * 64 +
                                         (((ks * 4 + lg) ^ (lr & 7)) * 8));
        }
        // ---- stage slots (write-safety ledger in header comment) ----
        if (h == 0) {
          if (p == 0)      { stA(2 * J + 1, 2); stA(2 * J + 1, 3); }
          else if (p == 1) { if (t2 < NTSW) { stB(t2, 0); stB(t2, 1); } }
          else if (p == 2) { if (t2 < NTSW) { stB(t2, 2); stB(t2, 3); } }
          else {
            if (t2 < NTSW) { stA(t2, 0); stA(t2, 1);
                             asm volatile("s_waitcnt vmcnt(6)" ::: "memory"); }
            else           { asm volatile("s_waitcnt vmcnt(0)" ::: "memory"); }
          }
        } else {
          if (p == 0)      { if (t2 < NTSW) { stA(t2, 2); stA(t2, 3); } }
          else if (p == 1) { if (t3 < NTSW) { stB(t3, 0); stB(t3, 1); } }
          else if (p == 2) { if (t3 < NTSW) { stB(t3, 2); stB(t3, 3); } }
          else {
            if (t3 < NTSW) { stA(t3, 0); stA(t3, 1);
                             asm volatile("s_waitcnt vmcnt(6)" ::: "memory"); }
            else           { asm volatile("s_waitcnt vmcnt(0)" ::: "memory"); }
          }
        }
        __builtin_amdgcn_s_barrier();
        asm volatile("s_waitcnt lgkmcnt(0)" ::: "memory");
        __builtin_amdgcn_sched_barrier(0);
        __builtin_amdgcn_s_setprio(1);
#pragma unroll
        for (int e = 0; e < 2; ++e)
#pragma unroll
          for (int j = 0; j < 4; ++j)
#pragma unroll
            for (int ks = 0; ks < 2; ++ks)
              acc[2 * p + e][j] = __builtin_amdgcn_mfma_f32_16x16x32_bf16(
                  af[e][ks], bfr[j][ks], acc[2 * p + e][j], 0, 0, 0);
        __builtin_amdgcn_s_setprio(0);
        __builtin_amdgcn_s_barrier();
      }
    }
  }

  // ---- SwiGLU epilogue: frag j even = gate, j odd = up ----
  const int cb = (col0 + wn) >> 1;
#pragma unroll
  for (int jp = 0; jp < 2; ++jp) {
    const int lcol = cb + jp * 16 + lr;
    const float gbv = gbias[lcol];
    const float ubv = ubias[lcol];
#pragma unroll
    for (int f = 0; f < 8; ++f) {
#pragma unroll
      for (int r = 0; r < 4; ++r) {
        const int row = row0 + wm + f * 16 + lg * 4 + r;
        float gv = acc[f][2 * jp][r] + gbv;
        gv = gv / (1.0f + __expf(-gv));
        const float uv = acc[f][2 * jp + 1][r] + ubv;
        G[(size_t)row * DFF + lcol] = f2bf(gv * uv);
      }
    }
  }
}

// ---------------------------------------------------------------------------
// down-proj split-K combine: out += sigmoid(gate) * (P0+P1+P2+P3 + db)
// ---------------------------------------------------------------------------
__global__ __launch_bounds__(256) void dcomb_k(
    const unsigned short* __restrict__ ws, float* __restrict__ out,
    const float* __restrict__ db, const float* __restrict__ gate)
{
  const int i4 = blockIdx.x * 256 + threadIdx.x;   // 1M threads x 4 elems
  const size_t idx = (size_t)i4 * 4;
  const int col = (int)(idx & 1023);
  const unsigned long long p0 = *(const unsigned long long*)(ws + 4u * 1048576u + idx);
  const unsigned long long p1 = *(const unsigned long long*)(ws + 8u * 1048576u + idx);
  const unsigned long long p2 = *(const unsigned long long*)(ws + 16u * 1048576u + idx);
  const unsigned long long p3 = *(const unsigned long long*)(ws + idx);
  float4 o = *(float4*)(out + idx);
  float* op = (float*)&o;
#pragma unroll
  for (int w = 0; w < 4; w++) {
    const float s = bf2f((unsigned short)(p0 >> (16 * w)))
                  + bf2f((unsigned short)(p1 >> (16 * w)))
                  + bf2f((unsigned short)(p2 >> (16 * w)))
                  + bf2f((unsigned short)(p3 >> (16 * w)))
                  + db[col + w];
    const float sg = 1.0f / (1.0f + __expf(-gate[col + w]));
    op[w] += sg * s;
  }
  *(float4*)(out + idx) = o;
}

// ---------------------------------------------------------------------------
template<int XF32>
__global__ __launch_bounds__(256) void rmsnorm_k(
    const void* __restrict__ Xv,
    const float* __restrict__ W,
    unsigned short* __restrict__ Y)
{
  const int t  = blockIdx.x;
  const int i0 = threadIdx.x * 4;

  float v[4];
  if (XF32) {
    const float4 f = *(const float4*)((const float*)Xv + (size_t)t * DIM + i0);
    v[0] = f.x; v[1] = f.y; v[2] = f.z; v[3] = f.w;
  } else {
    unsigned long long raw = *(const unsigned long long*)((const unsigned short*)Xv + (size_t)t * DIM + i0);
#pragma unroll
    for (int k = 0; k < 4; k++) v[k] = bf2f((unsigned short)(raw >> (16 * k)));
  }

  float ss = v[0] * v[0] + v[1] * v[1] + v[2] * v[2] + v[3] * v[3];
#pragma unroll
  for (int off = 32; off > 0; off >>= 1) ss += __shfl_xor(ss, off);

  __shared__ float red[4];
  if ((threadIdx.x & 63) == 0) red[threadIdx.x >> 6] = ss;
  __syncthreads();
  const float tot = red[0] + red[1] + red[2] + red[3];
  const float r = rsqrtf(tot * (1.0f / DIM) + 1e-5f);

  const float4 wf = *(const float4*)(W + i0);
  const float wv4[4] = {wf.x, wf.y, wf.z, wf.w};
  unsigned long long o = 0;
#pragma unroll
  for (int k = 0; k < 4; k++)
    o |= ((unsigned long long)f2bf(v[k] * r * wv4[k])) << (16 * k);
  *(unsigned long long*)(Y + (size_t)t * DIM + i0) = o;
}

// ---------------------------------------------------------------------------
// Split-K MFMA flash attention, fixed-max softmax, balanced static schedule.
// 32 chunks per (b,h): each 2..11 key-tiles (64 keys each), big-first order.
// qt 0..4 single chunk (direct normalized write). qt 5..15 split into 2-3
// chunks: base chunk writes unnormalized O to attn; extras write Pbuf;
// all write row-sums to Lbuf; combine kernel merges. K/V LDS double-buffered.
// GRID IS (bh, j): bh fastest -> all 32 bh's longest chunks dispatch first
// (tail holds only short chunks) and chunk c of bh lands on XCD bh%8 ->
// per-bh K/V is L2-resident. V staging is split issue-early/write-late
// (T14): global loads issue right after the barrier, the LDS scatter waits
// until after QK^T+softmax so HBM latency hides under compute.
// ---------------------------------------------------------------------------
__device__ const unsigned char cqt[32] = {10,10,15,15,9,9,13,14,14,14,15,4,8,8,12,12,13,13,7,7,11,11,11,12,3,6,6,5,5,2,1,0};
__device__ const unsigned char ctb[32] = {0,11,0,11,0,10,0,0,10,20,22,0,0,9,0,9,10,19,0,8,0,8,16,18,0,0,7,0,6,0,0,0};
__device__ const unsigned char ccnt[32] = {11,11,11,11,10,10,10,10,10,10,10,10,9,9,9,9,9,9,8,8,8,8,8,8,8,7,7,6,6,6,4,2};
__device__ const unsigned char cchv[32] = {0,1,0,1,0,1,0,0,1,2,2,0,0,1,0,1,1,2,0,1,0,1,2,2,0,0,1,0,1,0,0,0};
__device__ const unsigned char cpsv[32] = {255,5,255,14,255,4,255,255,12,13,15,255,255,3,255,8,10,11,255,2,255,6,7,9,255,255,1,255,0,255,255,255};

__global__ __launch_bounds__(256) void fattn_k(
    const unsigned short* __restrict__ QKV,   // [TTOK][3072]
    unsigned short* __restrict__ O,           // [TTOK][1024]
    unsigned short* __restrict__ Pbuf,        // 32bh x 16 slots x 128x64
    float* __restrict__ Lbuf)                 // 32bh x 11qt x 3ch x 128
{
  __shared__ __align__(16) unsigned short Ks[2][64 * 64];   // 16 KB
  __shared__ __align__(16) unsigned short Vt[2][64 * 72];   // 18 KB
  __shared__ __align__(16) unsigned short Ps[4 * 32 * 72];  // 18 KB

  const int tid  = threadIdx.x;
  const int lane = tid & 63;
  const int wv   = tid >> 6;
  const int lr   = lane & 15;
  const int lg   = lane >> 4;

  const int bh = blockIdx.x;                 // bh fastest: long chunks first
  const int j  = blockIdx.y;
  const int qt = cqt[j];
  const int tb = ctb[j];
  const int nt = ccnt[j];
  const int ch = cchv[j];
  const int ps = cpsv[j];
  const int b  = bh >> 4, h = bh & 15;
  const int q0 = qt * 128;
  const size_t rowb = (size_t)b * SEQ;
  const int qoff = h * HD;
  const int koff = 1024 + qoff;
  const int voff = 2048 + qoff;

  short8 aq[2][2];
#pragma unroll
  for (int rf = 0; rf < 2; rf++) {
    const size_t tok = rowb + q0 + wv * 32 + rf * 16 + lr;
    aq[rf][0] = *(const short8*)(QKV + tok * S3 + qoff + lg * 8);
    aq[rf][1] = *(const short8*)(QKV + tok * S3 + qoff + 32 + lg * 8);
  }

  f32x4 o[2][4];
  f32x4 lacc[2];
#pragma unroll
  for (int rf = 0; rf < 2; rf++) {
    lacc[rf] = (f32x4){0.f, 0.f, 0.f, 0.f};
#pragma unroll
    for (int d = 0; d < 4; d++) o[rf][d] = (f32x4){0.f, 0.f, 0.f, 0.f};
  }
  short8 onesb;
#pragma unroll
  for (int jj = 0; jj < 8; jj++) onesb[jj] = (short)0x3F80;   // bf16 1.0

  const int srow = lane >> 3;
  const int skg  = (lane & 7) ^ srow;
  const int kv   = tid >> 2;
  const int d0   = (tid & 3) * 16;
  const int klo  = kv & 7, khi = kv >> 3;

  const float C1 = 0.125f * 1.44269504f;   // scale * log2e
  const float C2 = 11.5415603f;            // 8 * log2e

  // K staging (async global->LDS) + V load-issue (regs, no wait here)
  auto stage_load = [&](int buf, int ti, short8& v0, short8& v1) {
    const int t0 = (tb + ti) * 64;
    unsigned short* ksb = &Ks[buf][0];
#pragma unroll
    for (int i = 0; i < 2; i++) {
      const int c = wv * 2 + i;
      const unsigned short* gk = QKV + (rowb + t0 + c * 8 + srow) * S3 + koff + skg * 8;
      __builtin_amdgcn_global_load_lds(AS1(gk), AS3(ksb + c * 512), 16, 0, 0);
    }
    const unsigned short* gv = QKV + (rowb + t0 + kv) * S3 + voff + d0;
    v0 = *(const short8*)gv;
    v1 = *(const short8*)(gv + 8);
  };
  // V scatter into transposed+swizzled LDS (consumes the loaded regs)
  auto stage_write = [&](int buf, short8 v0, short8 v1) {
    unsigned short* vtb = &Vt[buf][0];
#pragma unroll
    for (int w = 0; w < 8; w++) {
      const int da = d0 + w, db2 = d0 + 8 + w;
      vtb[da  * 72 + ((khi ^ ((da  >> 3) & 7)) * 8) + klo] = (unsigned short)v0[w];
      vtb[db2 * 72 + ((khi ^ ((db2 >> 3) & 7)) * 8) + klo] = (unsigned short)v1[w];
    }
  };

  short8 pv0, pv1;
  stage_load(0, 0, pv0, pv1);
  stage_write(0, pv0, pv1);

  for (int ti = 0; ti < nt; ti++) {
    __syncthreads();                       // buf[ti&1] ready for all waves
    const bool pf = (ti + 1 < nt);
    if (pf) stage_load((ti + 1) & 1, ti + 1, pv0, pv1);   // issue loads early

    const int t0 = (tb + ti) * 64;
    const unsigned short* ksb = &Ks[ti & 1][0];
    const unsigned short* vtb = &Vt[ti & 1][0];

    // ---- S = Q K^T ----
    f32x4 S[2][4];
#pragma unroll
    for (int sub = 0; sub < 4; sub++) {
      const int kr = sub * 16 + lr;
      const short8 bk0 = *(const short8*)(ksb + kr * 64 + ((lg       ^ (kr & 7)) * 8));
      const short8 bk1 = *(const short8*)(ksb + kr * 64 + (((4 + lg) ^ (kr & 7)) * 8));
#pragma unroll
      for (int rf = 0; rf < 2; rf++) {
        f32x4 s = (f32x4){0.f, 0.f, 0.f, 0.f};
        s = __builtin_amdgcn_mfma_f32_16x16x32_bf16(aq[rf][0], bk0, s, 0, 0, 0);
        s = __builtin_amdgcn_mfma_f32_16x16x32_bf16(aq[rf][1], bk1, s, 0, 0, 0);
        S[rf][sub] = s;
      }
    }

    // ---- P = exp2(S*C1 - C2), causal mask on diagonal zone ----
    unsigned short* pw = Ps + wv * (32 * 72);
#pragma unroll
    for (int rf = 0; rf < 2; rf++) {
      const int qmin = q0 + wv * 32 + rf * 16;
      const bool diag = (t0 + 63 > qmin);
#pragma unroll
      for (int sub = 0; sub < 4; sub++) {
#pragma unroll
        for (int r = 0; r < 4; r++) {
          float t = fmaf(S[rf][sub][r], C1, -C2);
          if (diag && (t0 + sub * 16 + lr > qmin + lg * 4 + r)) t = -INFINITY;
          const float p = exp2f(t);
          pw[(rf * 16 + lg * 4 + r) * 72 + sub * 16 + lr] = f2bf_trunc(p);
        }
      }
    }

    // ---- V scatter lands here: HBM latency hid under QK^T+softmax ----
    if (pf) stage_write((ti + 1) & 1, pv0, pv1);

    // ---- O += P V ;  l += P 1 (per-wave P region: no barrier needed) ----
#pragma unroll
    for (int kf = 0; kf < 2; kf++) {
      const short8 pa0 = *(const short8*)(pw + lr * 72 + kf * 32 + lg * 8);
      const short8 pa1 = *(const short8*)(pw + (16 + lr) * 72 + kf * 32 + lg * 8);
      lacc[0] = __builtin_amdgcn_mfma_f32_16x16x32_bf16(pa0, onesb, lacc[0], 0, 0, 0);
      lacc[1] = __builtin_amdgcn_mfma_f32_16x16x32_bf16(pa1, onesb, lacc[1], 0, 0, 0);
#pragma unroll
      for (int dsub = 0; dsub < 4; dsub++) {
        const int d = dsub * 16 + lr;
        const short8 bvf = *(const short8*)(vtb + d * 72 +
                             (((kf * 4 + lg) ^ ((d >> 3) & 7)) * 8));
        o[0][dsub] = __builtin_amdgcn_mfma_f32_16x16x32_bf16(pa0, bvf, o[0][dsub], 0, 0, 0);
        o[1][dsub] = __builtin_amdgcn_mfma_f32_16x16x32_bf16(pa1, bvf, o[1][dsub], 0, 0, 0);
      }
    }
  }

  // ---- epilogue ----
  if (ps == 255 && qt < 5) {                // single chunk: normalized write
#pragma unroll
    for (int rf = 0; rf < 2; rf++) {
      float inv[4];
#pragma unroll
      for (int r = 0; r < 4; r++) inv[r] = 1.0f / lacc[rf][r];
#pragma unroll
      for (int dsub = 0; dsub < 4; dsub++)
#pragma unroll
        for (int r = 0; r < 4; r++)
          O[(rowb + q0 + wv * 32 + rf * 16 + lg * 4 + r) * DIM + h * HD + dsub * 16 + lr] =
              f2bf(o[rf][dsub][r] * inv[r]);
    }
  } else {
    const int lbase = ((bh * 11 + (qt - 5)) * 3 + ch) * 128;
#pragma unroll
    for (int rf = 0; rf < 2; rf++) {
      const int rbase = wv * 32 + rf * 16 + lg * 4;
      if (lr == 0) {
#pragma unroll
        for (int r = 0; r < 4; r++) Lbuf[lbase + rbase + r] = lacc[rf][r];
      }
    }
    if (ps == 255) {                        // base chunk: unnormalized into O
#pragma unroll
      for (int rf = 0; rf < 2; rf++)
#pragma unroll
        for (int dsub = 0; dsub < 4; dsub++)
#pragma unroll
          for (int r = 0; r < 4; r++)
            O[(rowb + q0 + wv * 32 + rf * 16 + lg * 4 + r) * DIM + h * HD + dsub * 16 + lr] =
                f2bf(o[rf][dsub][r]);
    } else {                                // extra chunk: partial buffer
      unsigned short* pb = Pbuf + ((size_t)bh * 16 + ps) * 8192;
#pragma unroll
      for (int rf = 0; rf < 2; rf++) {
        const int rbase = wv * 32 + rf * 16 + lg * 4;
#pragma unroll
        for (int dsub = 0; dsub < 4; dsub++)
#pragma unroll
          for (int r = 0; r < 4; r++)
            pb[(rbase + r) * 64 + dsub * 16 + lr] = f2bf(o[rf][dsub][r]);
      }
    }
  }
}

// ---------------------------------------------------------------------------
// Combine for qt 5..15: O = (O_base + sum extras) / (sum l). Grid (11, 32).
// ---------------------------------------------------------------------------
__global__ __launch_bounds__(256) void fattn_combine_k(
    const unsigned short* __restrict__ Pbuf,
    const float* __restrict__ Lbuf,
    unsigned short* __restrict__ O)
{
  const int qt = 5 + blockIdx.x;
  const int bh = blockIdx.y;
  const int b  = bh >> 4, h = bh & 15;
  const int q0 = qt * 128;
  const size_t rowb = (size_t)b * SEQ;
  const int pbase_t[11] = {0, 1, 2, 3, 4, 5, 6, 8, 10, 12, 14};
  const int pb0 = pbase_t[qt - 5];
  const int np  = (qt < 11) ? 1 : 2;
  const int lbase = (bh * 11 + (qt - 5)) * 3 * 128;

  const unsigned short* p0 = Pbuf + ((size_t)bh * 16 + pb0) * 8192;
  const unsigned short* p1 = Pbuf + ((size_t)bh * 16 + pb0 + 1) * 8192;

#pragma unroll
  for (int it = 0; it < 4; it++) {
    const int idx = it * 2048 + threadIdx.x * 8;
    const int row = idx >> 6;
    const int col = idx & 63;
    float ls = Lbuf[lbase + row] + Lbuf[lbase + 128 + row];
    if (np == 2) ls += Lbuf[lbase + 256 + row];
    const float inv = 1.0f / ls;

    unsigned short* op = O + (rowb + q0 + row) * DIM + h * HD + col;
    const short8 vb = *(const short8*)op;
    const short8 e0 = *(const short8*)(p0 + idx);
    short8 e1;
    if (np == 2) e1 = *(const short8*)(p1 + idx);
    short8 r;
#pragma unroll
    for (int w = 0; w < 8; w++) {
      float s = bf2f((unsigned short)vb[w]) + bf2f((unsigned short)e0[w]);
      if (np == 2) s += bf2f((unsigned short)e1[w]);
      r[w] = (short)f2bf(s * inv);
    }
    *(short8*)op = r;
  }
}

// ---------------------------------------------------------------------------
// Workspace (bf16 elems, 1M = 1<<20), high-water 36M = 72 MB:
//  [0,3M)    wqkv weights -> Lbuf (fattn) -> down partial P3 [0,4M)
//  [3M,4M)   wo weight    -> (P3 tail)
//  [4M,12M)  gu interleaved (gate/up 16-row blocks) -> down partials P0,P1
//  [12M,16M) dw (live to the end)
//  [16M,20M) x1 -> fattn Pbuf -> x2 -> down partial P2
//  [20M,32M) qkv -> g[0..12M)
//  [32M,36M) attn -> g[12M..16M)
//  h2 lives in d_out (f32).
// ---------------------------------------------------------------------------
extern "C" void kernel_launch(void* const* d_in, const int* in_sizes, int n_in,
                              void* d_out, int out_size, void* d_ws, size_t ws_size,
                              hipStream_t stream)
{
  const float* h    = (const float*)d_in[0];
  const float* cosb = (const float*)d_in[1];
  const float* sinb = (const float*)d_in[2];
  const float* n1w  = (const float*)d_in[3];
  const float* n2w  = (const float*)d_in[8];
  const float* gb   = (const float*)d_in[10];
  const float* ub   = (const float*)d_in[12];
  const float* db   = (const float*)d_in[14];
  const float* gatep= (const float*)d_in[15];
  float* out = (float*)d_out;

  unsigned short* ws = (unsigned short*)d_ws;
  const size_t M1 = 1u << 20;

  unsigned short* wqkv = ws;                  // wq@0, wk@1M, wv@2M
  unsigned short* wo_c = ws + 3 * M1;
  unsigned short* gu_c = ws + 4 * M1;         // interleaved gate/up [8192][1024]
  unsigned short* dw_c = ws + 12 * M1;
  unsigned short* x1   = ws + 16 * M1;
  unsigned short* Pbuf = ws + 16 * M1;        // overlay (x1 dead during fattn)
  unsigned short* x2   = ws + 16 * M1;        // overlay (Pbuf dead after combine)
  float*          Lbuf = (float*)ws;          // overlay on dead wqkv
  unsigned short* qkv  = ws + 20 * M1;        // 12M
  unsigned short* attn = ws + 32 * M1;        // 4M
  unsigned short* g    = qkv;                 // 16M over qkv+attn (both dead)

  const dim3 blk(256);
  const dim3 gq(TTOK / 128, S3 / 128);        // (32, 24)
  const dim3 g1(TTOK / 128, DIM / 128);       // (32, 8)
  const dim3 gsw(TTOK / 256, 32);             // (16, 32) single SwiGLU launch
  const dim3 gd(TTOK / 128, DIM / 128, 4);    // (32, 8, 4) 128^2 split-K down

  // weights conv + rmsnorm1 fused (independent work, one launch)
  wconv_rms_k<<<16384 + TTOK, blk, 0, stream>>>(
      (const float*)d_in[4], (const float*)d_in[5], (const float*)d_in[6],
      (const float*)d_in[7], (const float*)d_in[9], (const float*)d_in[11],
      (const float*)d_in[13], ws, h, n1w, x1);

  // qkv = x1 @ [wq;wk;wv]^T with RoPE fused on Q,K cols
  gemm_bt<5><<<gq, blk, 0, stream>>>(x1, wqkv, qkv, nullptr, nullptr,
                                     cosb, sinb, TTOK, S3, DIM);

  // grid (bh, j): long chunks dispatch first; per-bh XCD affinity
  fattn_k<<<dim3(BATCH * HEADS, 32), blk, 0, stream>>>(qkv, attn, Pbuf, Lbuf);
  fattn_combine_k<<<dim3(11, BATCH * HEADS), blk, 0, stream>>>(Pbuf, Lbuf, attn);

  // h2(f32, in d_out) = attn @ wo^T + h
  gemm_bt<3><<<g1, blk, 0, stream>>>(attn, wo_c, nullptr, out, h,
                                     nullptr, nullptr, TTOK, DIM, DIM);

  rmsnorm_k<1><<<TTOK, blk, 0, stream>>>(out, n2w, x2);

  // g = silu(x2 gu^T + gb) * (x2 gu^T + ub) -- 256^2 8-phase, single launch
  gemm256_swiglu<<<gsw, dim3(512), 0, stream>>>(x2, gu_c, g, gb, ub, 0);

  // down-proj split-K x4 (128^2): bf16 partials into ws regions
  gemm_bt<6><<<gd, blk, 0, stream>>>(g, dw_c, ws, nullptr, nullptr,
                                     nullptr, nullptr, TTOK, DIM, DFF);

  // out += sigmoid(gate) * (P0+P1+P2+P3 + db)
  dcomb_k<<<4096, blk, 0, stream>>>(ws, out, db, gatep);
}

// Round 12
// 396.365 us; speedup vs baseline: 1.0419x; 1.0419x over previous
//
#include <hip/hip_runtime.h>
#include <math.h>

#define DIM    1024
#define HEADS  16
#define HD     64
#define SEQ    2048
#define BATCH  2
#define TTOK   4096   // BATCH*SEQ
#define DFF    4096
#define S3     3072   // fused QKV row stride
#define NTSW   16     // K-tiles per 1024-chunk (1024/64)

typedef __attribute__((ext_vector_type(8))) short short8;
typedef __attribute__((ext_vector_type(4))) float f32x4;

__device__ __forceinline__ float bf2f(unsigned short u) {
  union { unsigned int u; float f; } v; v.u = ((unsigned int)u) << 16; return v.f;
}
__device__ __forceinline__ unsigned short f2bf(float f) {
  union { float f; unsigned int u; } v; v.f = f;
  return (unsigned short)((v.u + 0x7FFFu + ((v.u >> 16) & 1u)) >> 16);
}
__device__ __forceinline__ unsigned short f2bf_trunc(float f) {
  union { float f; unsigned int u; } v; v.f = f;
  return (unsigned short)(v.u >> 16);
}

#define AS1(p) ((const __attribute__((address_space(1))) void*)(p))
#define AS3(p) ((__attribute__((address_space(3))) void*)(p))

// ---------------------------------------------------------------------------
// Merged weight conversion + rmsnorm1 (independent work, one launch).
// Blocks [0,16384): all 7 f32 weights -> contiguous bf16 [0,16M).
// Regions (4-elem units): wq/wk/wv/wo 262144 each; gate_w/up_w written
// INTERLEAVED at 16-row granularity into [1048576, 3145728) units (rows
// 32t+0..15 = gate rows 16t.., rows 32t+16..31 = up rows 16t..) so SwiGLU
// runs as ONE plain GEMM with N=8192; dw 1048576 units at 3145728.
// Blocks [16384,20480): rmsnorm over h (f32) -> x1 (bf16), t = blk-16384.
// ---------------------------------------------------------------------------
__global__ __launch_bounds__(256) void wconv_rms_k(
    const float* __restrict__ s0, const float* __restrict__ s1,
    const float* __restrict__ s2, const float* __restrict__ s3,
    const float* __restrict__ s4, const float* __restrict__ s5,
    const float* __restrict__ s6, unsigned short* __restrict__ dst,
    const float* __restrict__ X, const float* __restrict__ Wn,
    unsigned short* __restrict__ Y)
{
  __shared__ float red[4];
  if (blockIdx.x < 16384) {
    const int i = blockIdx.x * 256 + threadIdx.x;   // 0..4194303
    const float* s; int base; int di = i;
    if (i < 1048576) {
      if (i < 524288) { if (i < 262144) { s = s0; base = 0; } else { s = s1; base = 262144; } }
      else            { if (i < 786432) { s = s2; base = 524288; } else { s = s3; base = 786432; } }
    } else if (i < 2097152) {
      s = s4; base = 1048576;
      const int u = i - base; const int r = u >> 8; const int c = u & 255;
      di = 1048576 + (((r >> 4) << 5) + (r & 15)) * 256 + c;       // gate rows
    } else if (i < 3145728) {
      s = s5; base = 2097152;
      const int u = i - base; const int r = u >> 8; const int c = u & 255;
      di = 1048576 + (((r >> 4) << 5) + 16 + (r & 15)) * 256 + c;  // up rows
    } else {
      s = s6; base = 3145728;
    }
    const float4 f = ((const float4*)s)[i - base];
    unsigned long long o = (unsigned long long)f2bf(f.x)
                         | ((unsigned long long)f2bf(f.y) << 16)
                         | ((unsigned long long)f2bf(f.z) << 32)
                         | ((unsigned long long)f2bf(f.w) << 48);
    ((unsigned long long*)dst)[di] = o;
  } else {
    const int t  = blockIdx.x - 16384;
    const int i0 = threadIdx.x * 4;
    const float4 f = *(const float4*)(X + (size_t)t * DIM + i0);
    float v[4] = {f.x, f.y, f.z, f.w};
    float ss = v[0] * v[0] + v[1] * v[1] + v[2] * v[2] + v[3] * v[3];
#pragma unroll
    for (int off = 32; off > 0; off >>= 1) ss += __shfl_xor(ss, off);
    if ((threadIdx.x & 63) == 0) red[threadIdx.x >> 6] = ss;
    __syncthreads();
    const float tot = red[0] + red[1] + red[2] + red[3];
    const float r = rsqrtf(tot * (1.0f / DIM) + 1e-5f);
    const float4 wf = *(const float4*)(Wn + i0);
    const float wv4[4] = {wf.x, wf.y, wf.z, wf.w};
    unsigned long long o = 0;
#pragma unroll
    for (int k = 0; k < 4; k++)
      o |= ((unsigned long long)f2bf(v[k] * r * wv4[k])) << (16 * k);
    *(unsigned long long*)(Y + (size_t)t * DIM + i0) = o;
  }
}

// ---------------------------------------------------------------------------
// GEMM: C[M,N] = A[M,K] bf16 x W[N,K]^T bf16. 128x128 tile, BK=64, 4 waves,
// 16x16x32 MFMA, global_load_lds w=16, XOR-8 swizzle.
// MODE 3: Cf = v + resf (f32 out)
// MODE 5: C = v with RoPE on cols<2048 (fused QKV, N=3072)
// ---------------------------------------------------------------------------
template<int MODE>
__global__ __launch_bounds__(256) void gemm_bt(
    const unsigned short* __restrict__ A,
    const unsigned short* __restrict__ W,
    unsigned short* __restrict__ C,
    float* __restrict__ Cf,
    const float* __restrict__ resf,
    const float* __restrict__ cosp,
    const float* __restrict__ sinp,
    int M, int N, int K)
{
  __shared__ __align__(16) unsigned short As[128 * 64];
  __shared__ __align__(16) unsigned short Bs[128 * 64];

  const int tid  = threadIdx.x;
  const int lane = tid & 63;
  const int wv   = tid >> 6;
  const int row0 = blockIdx.x * 128;
  const int col0 = blockIdx.y * 128;
  const int wm   = (wv >> 1) * 64;
  const int wn   = (wv & 1) * 64;
  const int lr   = lane & 15;
  const int lg   = lane >> 4;

  const int srow = lane >> 3;
  const int skg  = (lane & 7) ^ srow;

  f32x4 acc[4][4];
#pragma unroll
  for (int i = 0; i < 4; i++)
#pragma unroll
    for (int j = 0; j < 4; j++) acc[i][j] = (f32x4){0.f, 0.f, 0.f, 0.f};

  for (int k0 = 0; k0 < K; k0 += 64) {
#pragma unroll
    for (int i = 0; i < 4; i++) {
      const int c = wv * 4 + i;
      const unsigned short* ga = A + (size_t)(row0 + c * 8 + srow) * K + k0 + skg * 8;
      __builtin_amdgcn_global_load_lds(AS1(ga), AS3(As + c * 512), 16, 0, 0);
      const unsigned short* gb = W + (size_t)(col0 + c * 8 + srow) * K + k0 + skg * 8;
      __builtin_amdgcn_global_load_lds(AS1(gb), AS3(Bs + c * 512), 16, 0, 0);
    }
    __syncthreads();

#pragma unroll
    for (int ks = 0; ks < 2; ks++) {
      short8 af[4], bf[4];
#pragma unroll
      for (int i = 0; i < 4; i++) {
        const int r = wm + i * 16 + lr;
        af[i] = *(const short8*)(As + r * 64 + (((ks * 4 + lg) ^ (lr & 7)) * 8));
      }
#pragma unroll
      for (int j = 0; j < 4; j++) {
        const int r = wn + j * 16 + lr;
        bf[j] = *(const short8*)(Bs + r * 64 + (((ks * 4 + lg) ^ (lr & 7)) * 8));
      }
#pragma unroll
      for (int i = 0; i < 4; i++)
#pragma unroll
        for (int j = 0; j < 4; j++)
          acc[i][j] = __builtin_amdgcn_mfma_f32_16x16x32_bf16(af[i], bf[j], acc[i][j], 0, 0, 0);
    }
    __syncthreads();
  }

  // epilogue: C/D layout col=lane&15, row=(lane>>4)*4+r  [m89/m91]
  if (MODE == 5) {
    const bool do_rope = (col0 < 2048);
#pragma unroll
    for (int i = 0; i < 4; i++) {
#pragma unroll
      for (int r = 0; r < 4; r++) {
        const int row = row0 + wm + i * 16 + lg * 4 + r;
        const int s = row & (SEQ - 1);
        const size_t rb = (size_t)row * N + col0 + wn;
        if (do_rope) {
#pragma unroll
          for (int jp = 0; jp < 2; jp++) {
            const int d = jp * 16 + lr;
            const float c = cosp[s * HD + d];
            const float sn = sinp[s * HD + d];
            const float x1v = acc[i][jp][r];
            const float x2v = acc[i][jp + 2][r];
            C[rb + d]      = f2bf(x1v * c - x2v * sn);
            C[rb + d + 32] = f2bf(x2v * c + x1v * sn);
          }
        } else {
#pragma unroll
          for (int j = 0; j < 4; j++)
            C[rb + j * 16 + lr] = f2bf(acc[i][j][r]);
        }
      }
    }
    return;
  }

#pragma unroll
  for (int i = 0; i < 4; i++) {
#pragma unroll
    for (int j = 0; j < 4; j++) {
      const int col = col0 + wn + j * 16 + lr;
#pragma unroll
      for (int r = 0; r < 4; r++) {
        const int row = row0 + wm + i * 16 + lg * 4 + r;
        const float v = acc[i][j][r];
        const size_t idx = (size_t)row * N + col;
        if (MODE == 3) {
          Cf[idx] = v + resf[idx];
        }
      }
    }
  }
}

// ---------------------------------------------------------------------------
// 256x256-tile 8-phase SwiGLU GEMM (m201 template port, T2+T3+T4+T5).
// 512 thr / 8 waves (2Mx4N), per-wave 128x64 out, BK=64, 2 K-tiles/iter,
// LDS 128KB (2 dbuf x 32KB x {A,B}). A stored as 4 phase-private 8KB
// quarters; B read whole in each tile's first phase, held in regs.
// vmcnt(6) gates at phases 4/8 only; tail gates drain to 0. XOR-8 chunk
// swizzle via pre-swizzled source; accumulation order identical to the
// 128^2 path (bitwise-same output).
// SwiGLU over 16-row interleaved gate/up W [8192][1024]: frag j even=gate /
// j odd=up on the same lanes; out G[M][DFF]. Scalar-store epilogue (via-LDS
// variant did not replicate at wall level; wall noise +-8-10us, R6-R10).
// ---------------------------------------------------------------------------
__global__ __launch_bounds__(512, 2) void gemm256_swiglu(
    const unsigned short* __restrict__ A,    // [4096][1024]
    const unsigned short* __restrict__ W,    // [8192][1024] interleaved gu
    unsigned short* __restrict__ G,          // [4096][4096]
    const float* __restrict__ gbias,
    const float* __restrict__ ubias,
    int colb)
{
  __shared__ __align__(16) unsigned short Asl[2 * 16384];  // 64 KB
  __shared__ __align__(16) unsigned short Bsl[2 * 16384];  // 64 KB

  const int tid  = threadIdx.x;
  const int lane = tid & 63;
  const int wv   = tid >> 6;
  const int row0 = blockIdx.x * 256;
  const int col0 = blockIdx.y * 256 + colb;
  const int wm   = (wv >> 2) * 128;          // 0 | 128
  const int wn   = (wv & 3) * 64;            // 0..192
  const int lr   = lane & 15;
  const int lg   = lane >> 4;

  // staging geometry: thread t covers shorts [t*8, t*8+8) of an 8KB quarter.
  // local row rl = t>>3 (0..63), stored chunk = t&7, logical chunk =
  // stored ^ (rl&7)  (XOR-8 swizzle via pre-swizzled global source).
  const int rl   = tid >> 3;
  const int rq   = (rl & 31) + ((rl >> 5) << 7);   // +q*32 = row within tile
  const int cl8  = ((tid & 7) ^ (rl & 7)) * 8;     // logical col byte-pair off
  const int ldsu = wv * 512;                       // wave-uniform LDS slice

  auto stA = [&](int t, int q) {
    const unsigned short* s = A + (size_t)(row0 + q * 32 + rq) * 1024 + t * 64 + cl8;
    __builtin_amdgcn_global_load_lds(AS1(s), AS3(Asl + (t & 1) * 16384 + q * 4096 + ldsu), 16, 0, 0);
  };
  auto stB = [&](int t, int q) {
    const unsigned short* s = W + (size_t)(col0 + q * 32 + rq) * 1024 + t * 64 + cl8;
    __builtin_amdgcn_global_load_lds(AS1(s), AS3(Bsl + (t & 1) * 16384 + q * 4096 + ldsu), 16, 0, 0);
  };

  f32x4 acc[8][4];
#pragma unroll
  for (int f = 0; f < 8; f++)
#pragma unroll
    for (int j = 0; j < 4; j++) acc[f][j] = (f32x4){0.f, 0.f, 0.f, 0.f};

  // prologue: T0 full (8 units) + T1 {B q0-3, A q0,q1} (6 units)
  stB(0, 0); stB(0, 1); stB(0, 2); stB(0, 3);
  stA(0, 0); stA(0, 1); stA(0, 2); stA(0, 3);
  stB(1, 0); stB(1, 1); stB(1, 2); stB(1, 3);
  stA(1, 0); stA(1, 1);
  asm volatile("s_waitcnt vmcnt(6)" ::: "memory");   // T0 landed; T1x6 in flight
  __builtin_amdgcn_s_barrier();

#pragma unroll 1
  for (int J = 0; J < NTSW / 2; ++J) {
    const int t2 = 2 * J + 2, t3 = 2 * J + 3;
#pragma unroll
    for (int h = 0; h < 2; ++h) {
      const unsigned short* Ab = Asl + h * 16384;   // tile 2J+h, buf = h
      const unsigned short* Bb = Bsl + h * 16384;
      short8 bfr[4][2];
#pragma unroll
      for (int p = 0; p < 4; ++p) {
        // ---- ds reads: B whole tile at p==0, A quarter p each phase ----
        if (p == 0) {
#pragma unroll
          for (int j = 0; j < 4; ++j) {
            const int rn   = wn + j * 16 + lr;
            const int q    = (rn & 127) >> 5;
            const int rloc = (rn & 31) + ((rn >> 7) << 5);
#pragma unroll
            for (int ks = 0; ks < 2; ++ks)
              bfr[j][ks] = *(const short8*)(Bb + q * 4096 + rloc * 64 +
                                            (((ks * 4 + lg) ^ (lr & 7)) * 8));
          }
        }
        short8 af[2][2];
#pragma unroll
        for (int e = 0; e < 2; ++e) {
          const int rloc = e * 16 + lr + ((wv >> 2) << 5);
#pragma unroll
          for (int ks = 0; ks < 2; ++ks)
            af[e][ks] = *(const short8*)(Ab + p * 4096 + rloc * 64 +
                                         (((ks * 4 + lg) ^ (lr & 7)) * 8));
        }
        // ---- stage slots (write-safety ledger in header comment) ----
        if (h == 0) {
          if (p == 0)      { stA(2 * J + 1, 2); stA(2 * J + 1, 3); }
          else if (p == 1) { if (t2 < NTSW) { stB(t2, 0); stB(t2, 1); } }
          else if (p == 2) { if (t2 < NTSW) { stB(t2, 2); stB(t2, 3); } }
          else {
            if (t2 < NTSW) { stA(t2, 0); stA(t2, 1);
                             asm volatile("s_waitcnt vmcnt(6)" ::: "memory"); }
            else           { asm volatile("s_waitcnt vmcnt(0)" ::: "memory"); }
          }
        } else {
          if (p == 0)      { if (t2 < NTSW) { stA(t2, 2); stA(t2, 3); } }
          else if (p == 1) { if (t3 < NTSW) { stB(t3, 0); stB(t3, 1); } }
          else if (p == 2) { if (t3 < NTSW) { stB(t3, 2); stB(t3, 3); } }
          else {
            if (t3 < NTSW) { stA(t3, 0); stA(t3, 1);
                             asm volatile("s_waitcnt vmcnt(6)" ::: "memory"); }
            else           { asm volatile("s_waitcnt vmcnt(0)" ::: "memory"); }
          }
        }
        __builtin_amdgcn_s_barrier();
        asm volatile("s_waitcnt lgkmcnt(0)" ::: "memory");
        __builtin_amdgcn_sched_barrier(0);
        __builtin_amdgcn_s_setprio(1);
#pragma unroll
        for (int e = 0; e < 2; ++e)
#pragma unroll
          for (int j = 0; j < 4; ++j)
#pragma unroll
            for (int ks = 0; ks < 2; ++ks)
              acc[2 * p + e][j] = __builtin_amdgcn_mfma_f32_16x16x32_bf16(
                  af[e][ks], bfr[j][ks], acc[2 * p + e][j], 0, 0, 0);
        __builtin_amdgcn_s_setprio(0);
        __builtin_amdgcn_s_barrier();
      }
    }
  }

  // ---- SwiGLU epilogue: frag j even = gate, j odd = up ----
  const int cb = (col0 + wn) >> 1;
#pragma unroll
  for (int jp = 0; jp < 2; ++jp) {
    const int lcol = cb + jp * 16 + lr;
    const float gbv = gbias[lcol];
    const float ubv = ubias[lcol];
#pragma unroll
    for (int f = 0; f < 8; ++f) {
#pragma unroll
      for (int r = 0; r < 4; ++r) {
        const int row = row0 + wm + f * 16 + lg * 4 + r;
        float gv = acc[f][2 * jp][r] + gbv;
        gv = gv / (1.0f + __expf(-gv));
        const float uv = acc[f][2 * jp + 1][r] + ubv;
        G[(size_t)row * DFF + lcol] = f2bf(gv * uv);
      }
    }
  }
}

// ---------------------------------------------------------------------------
// 256x256-tile 8-phase split-K down-proj GEMM (same template as swiglu;
// R3-verified). blockIdx.z selects a 1024-K-chunk (Kst=4096 row stride);
// bf16 partials into pz regions matching dcomb_k. Grid (16,4,4) = 256
// blocks = exactly 1 block/CU, one dispatch round.
// ---------------------------------------------------------------------------
__global__ __launch_bounds__(512, 2) void gemm256_down(
    const unsigned short* __restrict__ A,    // g [4096][4096]
    const unsigned short* __restrict__ W,    // dw [1024][4096]
    unsigned short* __restrict__ G)          // ws base (pz regions)
{
  __shared__ __align__(16) unsigned short Asl[2 * 16384];  // 64 KB
  __shared__ __align__(16) unsigned short Bsl[2 * 16384];  // 64 KB

  const int tid  = threadIdx.x;
  const int lane = tid & 63;
  const int wv   = tid >> 6;
  const int row0 = blockIdx.x * 256;
  const int col0 = blockIdx.y * 256;
  const int wm   = (wv >> 2) * 128;          // 0 | 128
  const int wn   = (wv & 3) * 64;            // 0..192
  const int lr   = lane & 15;
  const int lg   = lane >> 4;
  const int kb   = blockIdx.z * 1024;

  const int rl   = tid >> 3;
  const int rq   = (rl & 31) + ((rl >> 5) << 7);
  const int cl8  = ((tid & 7) ^ (rl & 7)) * 8;
  const int ldsu = wv * 512;

  auto stA = [&](int t, int q) {
    const unsigned short* s = A + (size_t)(row0 + q * 32 + rq) * 4096 + kb + t * 64 + cl8;
    __builtin_amdgcn_global_load_lds(AS1(s), AS3(Asl + (t & 1) * 16384 + q * 4096 + ldsu), 16, 0, 0);
  };
  auto stB = [&](int t, int q) {
    const unsigned short* s = W + (size_t)(col0 + q * 32 + rq) * 4096 + kb + t * 64 + cl8;
    __builtin_amdgcn_global_load_lds(AS1(s), AS3(Bsl + (t & 1) * 16384 + q * 4096 + ldsu), 16, 0, 0);
  };

  f32x4 acc[8][4];
#pragma unroll
  for (int f = 0; f < 8; f++)
#pragma unroll
    for (int j = 0; j < 4; j++) acc[f][j] = (f32x4){0.f, 0.f, 0.f, 0.f};

  // prologue: T0 full (8 units) + T1 {B q0-3, A q0,q1} (6 units)
  stB(0, 0); stB(0, 1); stB(0, 2); stB(0, 3);
  stA(0, 0); stA(0, 1); stA(0, 2); stA(0, 3);
  stB(1, 0); stB(1, 1); stB(1, 2); stB(1, 3);
  stA(1, 0); stA(1, 1);
  asm volatile("s_waitcnt vmcnt(6)" ::: "memory");
  __builtin_amdgcn_s_barrier();

#pragma unroll 1
  for (int J = 0; J < NTSW / 2; ++J) {
    const int t2 = 2 * J + 2, t3 = 2 * J + 3;
#pragma unroll
    for (int h = 0; h < 2; ++h) {
      const unsigned short* Ab = Asl + h * 16384;
      const unsigned short* Bb = Bsl + h * 16384;
      short8 bfr[4][2];
#pragma unroll
      for (int p = 0; p < 4; ++p) {
        if (p == 0) {
#pragma unroll
          for (int j = 0; j < 4; ++j) {
            const int rn   = wn + j * 16 + lr;
            const int q    = (rn & 127) >> 5;
            const int rloc = (rn & 31) + ((rn >> 7) << 5);
#pragma unroll
            for (int ks = 0; ks < 2; ++ks)
              bfr[j][ks] = *(const short8*)(Bb + q * 4096 + rloc * 64 +
                                            (((ks * 4 + lg) ^ (lr & 7)) * 8));
          }
        }
        short8 af[2][2];
#pragma unroll
        for (int e = 0; e < 2; ++e) {
          const int rloc = e * 16 + lr + ((wv >> 2) << 5);
#pragma unroll
          for (int ks = 0; ks < 2; ++ks)
            af[e][ks] = *(const short8*)(Ab + p * 4096 + rloc * 64 +
                                         (((ks * 4 + lg) ^ (lr & 7)) * 8));
        }
        if (h == 0) {
          if (p == 0)      { stA(2 * J + 1, 2); stA(2 * J + 1, 3); }
          else if (p == 1) { if (t2 < NTSW) { stB(t2, 0); stB(t2, 1); } }
          else if (p == 2) { if (t2 < NTSW) { stB(t2, 2); stB(t2, 3); } }
          else {
            if (t2 < NTSW) { stA(t2, 0); stA(t2, 1);
                             asm volatile("s_waitcnt vmcnt(6)" ::: "memory"); }
            else           { asm volatile("s_waitcnt vmcnt(0)" ::: "memory"); }
          }
        } else {
          if (p == 0)      { if (t2 < NTSW) { stA(t2, 2); stA(t2, 3); } }
          else if (p == 1) { if (t3 < NTSW) { stB(t3, 0); stB(t3, 1); } }
          else if (p == 2) { if (t3 < NTSW) { stB(t3, 2); stB(t3, 3); } }
          else {
            if (t3 < NTSW) { stA(t3, 0); stA(t3, 1);
                             asm volatile("s_waitcnt vmcnt(6)" ::: "memory"); }
            else           { asm volatile("s_waitcnt vmcnt(0)" ::: "memory"); }
          }
        }
        __builtin_amdgcn_s_barrier();
        asm volatile("s_waitcnt lgkmcnt(0)" ::: "memory");
        __builtin_amdgcn_sched_barrier(0);
        __builtin_amdgcn_s_setprio(1);
#pragma unroll
        for (int e = 0; e < 2; ++e)
#pragma unroll
          for (int j = 0; j < 4; ++j)
#pragma unroll
            for (int ks = 0; ks < 2; ++ks)
              acc[2 * p + e][j] = __builtin_amdgcn_mfma_f32_16x16x32_bf16(
                  af[e][ks], bfr[j][ks], acc[2 * p + e][j], 0, 0, 0);
        __builtin_amdgcn_s_setprio(0);
        __builtin_amdgcn_s_barrier();
      }
    }
  }

  // ---- split-K bf16 partial epilogue, N=1024, region per blockIdx.z ----
  const size_t pz[4] = {4u * 1048576u, 8u * 1048576u, 16u * 1048576u, 0u};
  unsigned short* Cz = G + pz[blockIdx.z];
#pragma unroll
  for (int j = 0; j < 4; ++j) {
    const int col = col0 + wn + j * 16 + lr;
#pragma unroll
    for (int f = 0; f < 8; ++f) {
#pragma unroll
      for (int r = 0; r < 4; ++r) {
        const int row = row0 + wm + f * 16 + lg * 4 + r;
        Cz[(size_t)row * DIM + col] = f2bf(acc[f][j][r]);
      }
    }
  }
}

// ---------------------------------------------------------------------------
// down-proj split-K combine: out += sigmoid(gate) * (P0+P1+P2+P3 + db)
// ---------------------------------------------------------------------------
__global__ __launch_bounds__(256) void dcomb_k(
    const unsigned short* __restrict__ ws, float* __restrict__ out,
    const float* __restrict__ db, const float* __restrict__ gate)
{
  const int i4 = blockIdx.x * 256 + threadIdx.x;   // 1M threads x 4 elems
  const size_t idx = (size_t)i4 * 4;
  const int col = (int)(idx & 1023);
  const unsigned long long p0 = *(const unsigned long long*)(ws + 4u * 1048576u + idx);
  const unsigned long long p1 = *(const unsigned long long*)(ws + 8u * 1048576u + idx);
  const unsigned long long p2 = *(const unsigned long long*)(ws + 16u * 1048576u + idx);
  const unsigned long long p3 = *(const unsigned long long*)(ws + idx);
  float4 o = *(float4*)(out + idx);
  float* op = (float*)&o;
#pragma unroll
  for (int w = 0; w < 4; w++) {
    const float s = bf2f((unsigned short)(p0 >> (16 * w)))
                  + bf2f((unsigned short)(p1 >> (16 * w)))
                  + bf2f((unsigned short)(p2 >> (16 * w)))
                  + bf2f((unsigned short)(p3 >> (16 * w)))
                  + db[col + w];
    const float sg = 1.0f / (1.0f + __expf(-gate[col + w]));
    op[w] += sg * s;
  }
  *(float4*)(out + idx) = o;
}

// ---------------------------------------------------------------------------
template<int XF32>
__global__ __launch_bounds__(256) void rmsnorm_k(
    const void* __restrict__ Xv,
    const float* __restrict__ W,
    unsigned short* __restrict__ Y)
{
  const int t  = blockIdx.x;
  const int i0 = threadIdx.x * 4;

  float v[4];
  if (XF32) {
    const float4 f = *(const float4*)((const float*)Xv + (size_t)t * DIM + i0);
    v[0] = f.x; v[1] = f.y; v[2] = f.z; v[3] = f.w;
  } else {
    unsigned long long raw = *(const unsigned long long*)((const unsigned short*)Xv + (size_t)t * DIM + i0);
#pragma unroll
    for (int k = 0; k < 4; k++) v[k] = bf2f((unsigned short)(raw >> (16 * k)));
  }

  float ss = v[0] * v[0] + v[1] * v[1] + v[2] * v[2] + v[3] * v[3];
#pragma unroll
  for (int off = 32; off > 0; off >>= 1) ss += __shfl_xor(ss, off);

  __shared__ float red[4];
  if ((threadIdx.x & 63) == 0) red[threadIdx.x >> 6] = ss;
  __syncthreads();
  const float tot = red[0] + red[1] + red[2] + red[3];
  const float r = rsqrtf(tot * (1.0f / DIM) + 1e-5f);

  const float4 wf = *(const float4*)(W + i0);
  const float wv4[4] = {wf.x, wf.y, wf.z, wf.w};
  unsigned long long o = 0;
#pragma unroll
  for (int k = 0; k < 4; k++)
    o |= ((unsigned long long)f2bf(v[k] * r * wv4[k])) << (16 * k);
  *(unsigned long long*)(Y + (size_t)t * DIM + i0) = o;
}

// ---------------------------------------------------------------------------
// Split-K MFMA flash attention, fixed-max softmax, balanced static schedule.
// 32 chunks per (b,h): each 2..11 key-tiles (64 keys each), big-first order.
// qt 0..4 single chunk (direct normalized write). qt 5..15 split into 2-3
// chunks: base chunk writes unnormalized O to attn; extras write Pbuf;
// all write row-sums to Lbuf; combine kernel merges. K/V LDS double-buffered.
// GRID IS (bh, j): bh fastest -> all 32 bh's longest chunks dispatch first
// (tail holds only short chunks) and chunk c of bh lands on XCD bh%8 ->
// per-bh K/V is L2-resident. V staging is split issue-early/write-late
// (T14): global loads issue right after the barrier, the LDS scatter waits
// until after QK^T+softmax so HBM latency hides under compute.
// ---------------------------------------------------------------------------
__device__ const unsigned char cqt[32] = {10,10,15,15,9,9,13,14,14,14,15,4,8,8,12,12,13,13,7,7,11,11,11,12,3,6,6,5,5,2,1,0};
__device__ const unsigned char ctb[32] = {0,11,0,11,0,10,0,0,10,20,22,0,0,9,0,9,10,19,0,8,0,8,16,18,0,0,7,0,6,0,0,0};
__device__ const unsigned char ccnt[32] = {11,11,11,11,10,10,10,10,10,10,10,10,9,9,9,9,9,9,8,8,8,8,8,8,8,7,7,6,6,6,4,2};
__device__ const unsigned char cchv[32] = {0,1,0,1,0,1,0,0,1,2,2,0,0,1,0,1,1,2,0,1,0,1,2,2,0,0,1,0,1,0,0,0};
__device__ const unsigned char cpsv[32] = {255,5,255,14,255,4,255,255,12,13,15,255,255,3,255,8,10,11,255,2,255,6,7,9,255,255,1,255,0,255,255,255};

__global__ __launch_bounds__(256) void fattn_k(
    const unsigned short* __restrict__ QKV,   // [TTOK][3072]
    unsigned short* __restrict__ O,           // [TTOK][1024]
    unsigned short* __restrict__ Pbuf,        // 32bh x 16 slots x 128x64
    float* __restrict__ Lbuf)                 // 32bh x 11qt x 3ch x 128
{
  __shared__ __align__(16) unsigned short Ks[2][64 * 64];   // 16 KB
  __shared__ __align__(16) unsigned short Vt[2][64 * 72];   // 18 KB
  __shared__ __align__(16) unsigned short Ps[4 * 32 * 72];  // 18 KB

  const int tid  = threadIdx.x;
  const int lane = tid & 63;
  const int wv   = tid >> 6;
  const int lr   = lane & 15;
  const int lg   = lane >> 4;

  const int bh = blockIdx.x;                 // bh fastest: long chunks first
  const int j  = blockIdx.y;
  const int qt = cqt[j];
  const int tb = ctb[j];
  const int nt = ccnt[j];
  const int ch = cchv[j];
  const int ps = cpsv[j];
  const int b  = bh >> 4, h = bh & 15;
  const int q0 = qt * 128;
  const size_t rowb = (size_t)b * SEQ;
  const int qoff = h * HD;
  const int koff = 1024 + qoff;
  const int voff = 2048 + qoff;

  short8 aq[2][2];
#pragma unroll
  for (int rf = 0; rf < 2; rf++) {
    const size_t tok = rowb + q0 + wv * 32 + rf * 16 + lr;
    aq[rf][0] = *(const short8*)(QKV + tok * S3 + qoff + lg * 8);
    aq[rf][1] = *(const short8*)(QKV + tok * S3 + qoff + 32 + lg * 8);
  }

  f32x4 o[2][4];
  f32x4 lacc[2];
#pragma unroll
  for (int rf = 0; rf < 2; rf++) {
    lacc[rf] = (f32x4){0.f, 0.f, 0.f, 0.f};
#pragma unroll
    for (int d = 0; d < 4; d++) o[rf][d] = (f32x4){0.f, 0.f, 0.f, 0.f};
  }
  short8 onesb;
#pragma unroll
  for (int jj = 0; jj < 8; jj++) onesb[jj] = (short)0x3F80;   // bf16 1.0

  const int srow = lane >> 3;
  const int skg  = (lane & 7) ^ srow;
  const int kv   = tid >> 2;
  const int d0   = (tid & 3) * 16;
  const int klo  = kv & 7, khi = kv >> 3;

  const float C1 = 0.125f * 1.44269504f;   // scale * log2e
  const float C2 = 11.5415603f;            // 8 * log2e

  // K staging (async global->LDS) + V load-issue (regs, no wait here)
  auto stage_load = [&](int buf, int ti, short8& v0, short8& v1) {
    const int t0 = (tb + ti) * 64;
    unsigned short* ksb = &Ks[buf][0];
#pragma unroll
    for (int i = 0; i < 2; i++) {
      const int c = wv * 2 + i;
      const unsigned short* gk = QKV + (rowb + t0 + c * 8 + srow) * S3 + koff + skg * 8;
      __builtin_amdgcn_global_load_lds(AS1(gk), AS3(ksb + c * 512), 16, 0, 0);
    }
    const unsigned short* gv = QKV + (rowb + t0 + kv) * S3 + voff + d0;
    v0 = *(const short8*)gv;
    v1 = *(const short8*)(gv + 8);
  };
  // V scatter into transposed+swizzled LDS (consumes the loaded regs)
  auto stage_write = [&](int buf, short8 v0, short8 v1) {
    unsigned short* vtb = &Vt[buf][0];
#pragma unroll
    for (int w = 0; w < 8; w++) {
      const int da = d0 + w, db2 = d0 + 8 + w;
      vtb[da  * 72 + ((khi ^ ((da  >> 3) & 7)) * 8) + klo] = (unsigned short)v0[w];
      vtb[db2 * 72 + ((khi ^ ((db2 >> 3) & 7)) * 8) + klo] = (unsigned short)v1[w];
    }
  };

  short8 pv0, pv1;
  stage_load(0, 0, pv0, pv1);
  stage_write(0, pv0, pv1);

  for (int ti = 0; ti < nt; ti++) {
    __syncthreads();                       // buf[ti&1] ready for all waves
    const bool pf = (ti + 1 < nt);
    if (pf) stage_load((ti + 1) & 1, ti + 1, pv0, pv1);   // issue loads early

    const int t0 = (tb + ti) * 64;
    const unsigned short* ksb = &Ks[ti & 1][0];
    const unsigned short* vtb = &Vt[ti & 1][0];

    // ---- S = Q K^T ----
    f32x4 S[2][4];
#pragma unroll
    for (int sub = 0; sub < 4; sub++) {
      const int kr = sub * 16 + lr;
      const short8 bk0 = *(const short8*)(ksb + kr * 64 + ((lg       ^ (kr & 7)) * 8));
      const short8 bk1 = *(const short8*)(ksb + kr * 64 + (((4 + lg) ^ (kr & 7)) * 8));
#pragma unroll
      for (int rf = 0; rf < 2; rf++) {
        f32x4 s = (f32x4){0.f, 0.f, 0.f, 0.f};
        s = __builtin_amdgcn_mfma_f32_16x16x32_bf16(aq[rf][0], bk0, s, 0, 0, 0);
        s = __builtin_amdgcn_mfma_f32_16x16x32_bf16(aq[rf][1], bk1, s, 0, 0, 0);
        S[rf][sub] = s;
      }
    }

    // ---- P = exp2(S*C1 - C2), causal mask on diagonal zone ----
    unsigned short* pw = Ps + wv * (32 * 72);
#pragma unroll
    for (int rf = 0; rf < 2; rf++) {
      const int qmin = q0 + wv * 32 + rf * 16;
      const bool diag = (t0 + 63 > qmin);
#pragma unroll
      for (int sub = 0; sub < 4; sub++) {
#pragma unroll
        for (int r = 0; r < 4; r++) {
          float t = fmaf(S[rf][sub][r], C1, -C2);
          if (diag && (t0 + sub * 16 + lr > qmin + lg * 4 + r)) t = -INFINITY;
          const float p = exp2f(t);
          pw[(rf * 16 + lg * 4 + r) * 72 + sub * 16 + lr] = f2bf_trunc(p);
        }
      }
    }

    // ---- V scatter lands here: HBM latency hid under QK^T+softmax ----
    if (pf) stage_write((ti + 1) & 1, pv0, pv1);

    // ---- O += P V ;  l += P 1 (per-wave P region: no barrier needed) ----
#pragma unroll
    for (int kf = 0; kf < 2; kf++) {
      const short8 pa0 = *(const short8*)(pw + lr * 72 + kf * 32 + lg * 8);
      const short8 pa1 = *(const short8*)(pw + (16 + lr) * 72 + kf * 32 + lg * 8);
      lacc[0] = __builtin_amdgcn_mfma_f32_16x16x32_bf16(pa0, onesb, lacc[0], 0, 0, 0);
      lacc[1] = __builtin_amdgcn_mfma_f32_16x16x32_bf16(pa1, onesb, lacc[1], 0, 0, 0);
#pragma unroll
      for (int dsub = 0; dsub < 4; dsub++) {
        const int d = dsub * 16 + lr;
        const short8 bvf = *(const short8*)(vtb + d * 72 +
                             (((kf * 4 + lg) ^ ((d >> 3) & 7)) * 8));
        o[0][dsub] = __builtin_amdgcn_mfma_f32_16x16x32_bf16(pa0, bvf, o[0][dsub], 0, 0, 0);
        o[1][dsub] = __builtin_amdgcn_mfma_f32_16x16x32_bf16(pa1, bvf, o[1][dsub], 0, 0, 0);
      }
    }
  }

  // ---- epilogue ----
  if (ps == 255 && qt < 5) {                // single chunk: normalized write
#pragma unroll
    for (int rf = 0; rf < 2; rf++) {
      float inv[4];
#pragma unroll
      for (int r = 0; r < 4; r++) inv[r] = 1.0f / lacc[rf][r];
#pragma unroll
      for (int dsub = 0; dsub < 4; dsub++)
#pragma unroll
        for (int r = 0; r < 4; r++)
          O[(rowb + q0 + wv * 32 + rf * 16 + lg * 4 + r) * DIM + h * HD + dsub * 16 + lr] =
              f2bf(o[rf][dsub][r] * inv[r]);
    }
  } else {
    const int lbase = ((bh * 11 + (qt - 5)) * 3 + ch) * 128;
#pragma unroll
    for (int rf = 0; rf < 2; rf++) {
      const int rbase = wv * 32 + rf * 16 + lg * 4;
      if (lr == 0) {
#pragma unroll
        for (int r = 0; r < 4; r++) Lbuf[lbase + rbase + r] = lacc[rf][r];
      }
    }
    if (ps == 255) {                        // base chunk: unnormalized into O
#pragma unroll
      for (int rf = 0; rf < 2; rf++)
#pragma unroll
        for (int dsub = 0; dsub < 4; dsub++)
#pragma unroll
          for (int r = 0; r < 4; r++)
            O[(rowb + q0 + wv * 32 + rf * 16 + lg * 4 + r) * DIM + h * HD + dsub * 16 + lr] =
                f2bf(o[rf][dsub][r]);
    } else {                                // extra chunk: partial buffer
      unsigned short* pb = Pbuf + ((size_t)bh * 16 + ps) * 8192;
#pragma unroll
      for (int rf = 0; rf < 2; rf++) {
        const int rbase = wv * 32 + rf * 16 + lg * 4;
#pragma unroll
        for (int dsub = 0; dsub < 4; dsub++)
#pragma unroll
          for (int r = 0; r < 4; r++)
            pb[(rbase + r) * 64 + dsub * 16 + lr] = f2bf(o[rf][dsub][r]);
      }
    }
  }
}

// ---------------------------------------------------------------------------
// Combine for qt 5..15: O = (O_base + sum extras) / (sum l). Grid (11, 32).
// ---------------------------------------------------------------------------
__global__ __launch_bounds__(256) void fattn_combine_k(
    const unsigned short* __restrict__ Pbuf,
    const float* __restrict__ Lbuf,
    unsigned short* __restrict__ O)
{
  const int qt = 5 + blockIdx.x;
  const int bh = blockIdx.y;
  const int b  = bh >> 4, h = bh & 15;
  const int q0 = qt * 128;
  const size_t rowb = (size_t)b * SEQ;
  const int pbase_t[11] = {0, 1, 2, 3, 4, 5, 6, 8, 10, 12, 14};
  const int pb0 = pbase_t[qt - 5];
  const int np  = (qt < 11) ? 1 : 2;
  const int lbase = (bh * 11 + (qt - 5)) * 3 * 128;

  const unsigned short* p0 = Pbuf + ((size_t)bh * 16 + pb0) * 8192;
  const unsigned short* p1 = Pbuf + ((size_t)bh * 16 + pb0 + 1) * 8192;

#pragma unroll
  for (int it = 0; it < 4; it++) {
    const int idx = it * 2048 + threadIdx.x * 8;
    const int row = idx >> 6;
    const int col = idx & 63;
    float ls = Lbuf[lbase + row] + Lbuf[lbase + 128 + row];
    if (np == 2) ls += Lbuf[lbase + 256 + row];
    const float inv = 1.0f / ls;

    unsigned short* op = O + (rowb + q0 + row) * DIM + h * HD + col;
    const short8 vb = *(const short8*)op;
    const short8 e0 = *(const short8*)(p0 + idx);
    short8 e1;
    if (np == 2) e1 = *(const short8*)(p1 + idx);
    short8 r;
#pragma unroll
    for (int w = 0; w < 8; w++) {
      float s = bf2f((unsigned short)vb[w]) + bf2f((unsigned short)e0[w]);
      if (np == 2) s += bf2f((unsigned short)e1[w]);
      r[w] = (short)f2bf(s * inv);
    }
    *(short8*)op = r;
  }
}

// ---------------------------------------------------------------------------
// Workspace (bf16 elems, 1M = 1<<20), high-water 36M = 72 MB:
//  [0,3M)    wqkv weights -> Lbuf (fattn) -> down partial P3 [0,4M)
//  [3M,4M)   wo weight    -> (P3 tail)
//  [4M,12M)  gu interleaved (gate/up 16-row blocks) -> down partials P0,P1
//  [12M,16M) dw (live to the end)
//  [16M,20M) x1 -> fattn Pbuf -> x2 -> down partial P2
//  [20M,32M) qkv -> g[0..12M)
//  [32M,36M) attn -> g[12M..16M)
//  h2 lives in d_out (f32).
// ---------------------------------------------------------------------------
extern "C" void kernel_launch(void* const* d_in, const int* in_sizes, int n_in,
                              void* d_out, int out_size, void* d_ws, size_t ws_size,
                              hipStream_t stream)
{
  const float* h    = (const float*)d_in[0];
  const float* cosb = (const float*)d_in[1];
  const float* sinb = (const float*)d_in[2];
  const float* n1w  = (const float*)d_in[3];
  const float* n2w  = (const float*)d_in[8];
  const float* gb   = (const float*)d_in[10];
  const float* ub   = (const float*)d_in[12];
  const float* db   = (const float*)d_in[14];
  const float* gatep= (const float*)d_in[15];
  float* out = (float*)d_out;

  unsigned short* ws = (unsigned short*)d_ws;
  const size_t M1 = 1u << 20;

  unsigned short* wqkv = ws;                  // wq@0, wk@1M, wv@2M
  unsigned short* wo_c = ws + 3 * M1;
  unsigned short* gu_c = ws + 4 * M1;         // interleaved gate/up [8192][1024]
  unsigned short* dw_c = ws + 12 * M1;
  unsigned short* x1   = ws + 16 * M1;
  unsigned short* Pbuf = ws + 16 * M1;        // overlay (x1 dead during fattn)
  unsigned short* x2   = ws + 16 * M1;        // overlay (Pbuf dead after combine)
  float*          Lbuf = (float*)ws;          // overlay on dead wqkv
  unsigned short* qkv  = ws + 20 * M1;        // 12M
  unsigned short* attn = ws + 32 * M1;        // 4M
  unsigned short* g    = qkv;                 // 16M over qkv+attn (both dead)

  const dim3 blk(256);
  const dim3 gq(TTOK / 128, S3 / 128);        // (32, 24)
  const dim3 g1(TTOK / 128, DIM / 128);       // (32, 8)
  const dim3 gsw(TTOK / 256, 32);             // (16, 32) single SwiGLU launch
  const dim3 gd(TTOK / 256, DIM / 256, 4);    // (16, 4, 4) 256^2 split-K down

  // weights conv + rmsnorm1 fused (independent work, one launch)
  wconv_rms_k<<<16384 + TTOK, blk, 0, stream>>>(
      (const float*)d_in[4], (const float*)d_in[5], (const float*)d_in[6],
      (const float*)d_in[7], (const float*)d_in[9], (const float*)d_in[11],
      (const float*)d_in[13], ws, h, n1w, x1);

  // qkv = x1 @ [wq;wk;wv]^T with RoPE fused on Q,K cols
  gemm_bt<5><<<gq, blk, 0, stream>>>(x1, wqkv, qkv, nullptr, nullptr,
                                     cosb, sinb, TTOK, S3, DIM);

  // grid (bh, j): long chunks dispatch first; per-bh XCD affinity
  fattn_k<<<dim3(BATCH * HEADS, 32), blk, 0, stream>>>(qkv, attn, Pbuf, Lbuf);
  fattn_combine_k<<<dim3(11, BATCH * HEADS), blk, 0, stream>>>(Pbuf, Lbuf, attn);

  // h2(f32, in d_out) = attn @ wo^T + h
  gemm_bt<3><<<g1, blk, 0, stream>>>(attn, wo_c, nullptr, out, h,
                                     nullptr, nullptr, TTOK, DIM, DIM);

  rmsnorm_k<1><<<TTOK, blk, 0, stream>>>(out, n2w, x2);

  // g = silu(x2 gu^T + gb) * (x2 gu^T + ub) -- 256^2 8-phase, single launch
  gemm256_swiglu<<<gsw, dim3(512), 0, stream>>>(x2, gu_c, g, gb, ub, 0);

  // down-proj split-K x4 (256^2 8-phase, 256 blocks = 1 round): partials
  gemm256_down<<<gd, dim3(512), 0, stream>>>(g, dw_c, ws);

  // out += sigmoid(gate) * (P0+P1+P2+P3 + db)
  dcomb_k<<<4096, blk, 0, stream>>>(ws, out, db, gatep);
}